// Round 1
// baseline (823.521 us; speedup 1.0000x reference)
//
#include <hip/hip_runtime.h>
#include <hip/hip_bf16.h>

#define BATCH 8192
#define NUM_LABELS 8190
#define CURW 2944   // padded cur width (K for level 5)
#define YW   8192   // ybuf row stride

typedef __attribute__((ext_vector_type(4))) float f32x4;
typedef __attribute__((ext_vector_type(8))) short bf16x8;

// ---------- helpers ----------
__device__ __forceinline__ unsigned short f2bf(float f) {
  unsigned u = __builtin_bit_cast(unsigned, f);
  unsigned r = u + 0x7fffu + ((u >> 16) & 1u);   // RNE; inputs are finite
  return (unsigned short)(r >> 16);
}
__device__ __forceinline__ float bf2f(unsigned short b) {
  return __builtin_bit_cast(float, (unsigned)b << 16);
}
__device__ __forceinline__ void gload_lds16(const void* g, void* l) {
  __builtin_amdgcn_global_load_lds(
      (const __attribute__((address_space(1))) void*)g,
      (__attribute__((address_space(3))) void*)l,
      16, 0, 0);
}

// ---------- x -> bf16 raw + relu'd cur ----------
__global__ void k_convert_x(const float* __restrict__ x,
                            unsigned short* __restrict__ xraw,
                            unsigned short* __restrict__ cur) {
  int i = blockIdx.x * 256 + threadIdx.x;
  const int total = BATCH * 768 / 4;
  if (i >= total) return;
  float4 v = ((const float4*)x)[i];
  int e = i * 4;
  int row = e / 768;
  int col = e - row * 768;
  ushort4 a, c;
  a.x = f2bf(v.x); a.y = f2bf(v.y); a.z = f2bf(v.z); a.w = f2bf(v.w);
  c.x = f2bf(fmaxf(v.x, 0.f)); c.y = f2bf(fmaxf(v.y, 0.f));
  c.z = f2bf(fmaxf(v.z, 0.f)); c.w = f2bf(fmaxf(v.w, 0.f));
  *(ushort4*)(xraw + e) = a;
  *(ushort4*)(cur + (size_t)row * CURW + col) = c;
}

// ---------- zero the K-pad columns of cur ----------
__global__ void k_zero_pads(unsigned short* __restrict__ cur) {
  const int PP = 130;  // 58 + 40 + 32 pad cols per row
  int i = blockIdx.x * 256 + threadIdx.x;
  if (i >= BATCH * PP) return;
  int row = i / PP, p = i - row * PP;
  int col = p < 58 ? 774 + p : (p < 98 ? 856 + (p - 58) : 992 + (p - 98));
  cur[(size_t)row * CURW + col] = 0;
}

// ---------- padded-col -> real-col map (global, level-independent prefix) ----------
__device__ __forceinline__ int pad2real(int kp) {
  if (kp < 774)  return kp;               // x(768) + y0(6)
  if (kp < 832)  return -1;               // pad
  if (kp < 856)  return 774 + (kp - 832); // y1(24)
  if (kp < 896)  return -1;
  if (kp < 992)  return 798 + (kp - 896); // y2(96)
  if (kp < 1024) return -1;
  if (kp < 1408) return 894 + (kp - 1024);  // y3(384)
  return 1278 + (kp - 1408);                // y4(1536) -> up to 2814
}

__global__ void k_convert_w(const float* __restrict__ W, unsigned short* __restrict__ Wp,
                            int Nreal, int Kreal, int Kpad, int total) {
  int i = blockIdx.x * 256 + threadIdx.x;
  if (i >= total) return;
  int n = i / Kpad, kp = i - n * Kpad;
  int kr = pad2real(kp);
  float v = 0.f;
  if (n < Nreal && kr >= 0) v = W[(size_t)n * Kreal + kr];
  Wp[i] = f2bf(v);
}

// ---------- inverse permutation ----------
__global__ void k_inv(const int* __restrict__ labels, int* __restrict__ inv) {
  int t = blockIdx.x * 256 + threadIdx.x;
  if (t < NUM_LABELS) inv[labels[t]] = t;
}

// ---------- GEMM: C[M,N] = A[M,K] * B[N,K]^T + bias; dual epilogue ----------
// 128x128 tile, 4 waves (2x2), BK=64, 16x16x32 bf16 MFMA, global_load_lds staging.
__global__ __launch_bounds__(256, 2) void k_gemm(
    const unsigned short* __restrict__ A, int lda,
    const unsigned short* __restrict__ B, int ldb,
    const float* __restrict__ bias,
    unsigned short* __restrict__ ybuf,
    unsigned short* __restrict__ curout,   // null for last level
    int K, int Nreal, int yoff, int curoff) {
  __shared__ unsigned short Asmem[128 * 64];
  __shared__ unsigned short Bsmem[128 * 64];
  const int tid = threadIdx.x;
  const int lane = tid & 63;
  const int wid = tid >> 6;
  const int wr = wid >> 1, wc = wid & 1;
  const int brow = blockIdx.x * 128;
  const int bcol = blockIdx.y * 128;

  f32x4 acc[4][4] = {};

  for (int k0 = 0; k0 < K; k0 += 64) {
#pragma unroll
    for (int p = 0; p < 4; ++p) {
      int ch = wid * 4 + p;
      int eo = ch * 512 + lane * 8;   // element offset in 128x64 tile
      int r = eo >> 6;
      int col = eo & 63;
      gload_lds16(A + (size_t)(brow + r) * lda + k0 + col, Asmem + ch * 512);
      gload_lds16(B + (size_t)(bcol + r) * ldb + k0 + col, Bsmem + ch * 512);
    }
    __syncthreads();
#pragma unroll
    for (int kk = 0; kk < 2; ++kk) {
      bf16x8 af[4], bfr[4];
      int colk = kk * 32 + (lane >> 4) * 8;
#pragma unroll
      for (int m = 0; m < 4; ++m)
        af[m] = *(const bf16x8*)(Asmem + (wr * 64 + m * 16 + (lane & 15)) * 64 + colk);
#pragma unroll
      for (int n = 0; n < 4; ++n)
        bfr[n] = *(const bf16x8*)(Bsmem + (wc * 64 + n * 16 + (lane & 15)) * 64 + colk);
#pragma unroll
      for (int m = 0; m < 4; ++m)
#pragma unroll
        for (int n = 0; n < 4; ++n)
          acc[m][n] = __builtin_amdgcn_mfma_f32_16x16x32_bf16(af[m], bfr[n], acc[m][n], 0, 0, 0);
    }
    __syncthreads();
  }

  // epilogue: y -> ybuf (raw bf16), relu(y) -> cur segment
#pragma unroll
  for (int n = 0; n < 4; ++n) {
    int col = bcol + wc * 64 + n * 16 + (lane & 15);
    if (col >= Nreal) continue;
    float bv = bias[col];
#pragma unroll
    for (int m = 0; m < 4; ++m) {
#pragma unroll
      for (int j = 0; j < 4; ++j) {
        int row = brow + wr * 64 + m * 16 + (lane >> 4) * 4 + j;
        float y = acc[m][n][j] + bv;
        ybuf[(size_t)row * YW + yoff + col] = f2bf(y);
        if (curout) curout[(size_t)row * CURW + curoff + col] = f2bf(fmaxf(y, 0.f));
      }
    }
  }
}

// ---------- final gather: out[row][c] = ybuf[row][inv[c]] ----------
__global__ void k_gather(const unsigned short* __restrict__ ybuf,
                         const int* __restrict__ inv,
                         float* __restrict__ out) {
  int i = blockIdx.x * 256 + threadIdx.x;
  if (i >= BATCH * NUM_LABELS) return;
  int row = i / NUM_LABELS;
  int c = i - row * NUM_LABELS;
  out[i] = bf2f(ybuf[(size_t)row * YW + inv[c]]);
}

// ---------- launch ----------
extern "C" void kernel_launch(void* const* d_in, const int* in_sizes, int n_in,
                              void* d_out, int out_size, void* d_ws, size_t ws_size,
                              hipStream_t stream) {
  const float* x = (const float*)d_in[0];
  const float* W[6];
  const float* bias[6];
  for (int i = 0; i < 6; ++i) {
    W[i] = (const float*)d_in[1 + 2 * i];
    bias[i] = (const float*)d_in[2 + 2 * i];
  }
  const int* labels = (const int*)d_in[13];
  float* out = (float*)d_out;

  char* ws = (char*)d_ws;
  unsigned short* xraw = (unsigned short*)(ws);                 // 12,582,912 B
  unsigned short* cur  = (unsigned short*)(ws + 12582912);      // 48,234,496 B
  unsigned short* wp   = (unsigned short*)(ws + 60817408);      // 41,926,656 B
  unsigned short* ybuf = (unsigned short*)(ws + 102744064);     // 134,217,728 B
  int* inv             = (int*)(ws + 236961792);                // 32,768 B

  static const int Kreal[6]  = {768, 774, 798, 894, 1278, 2814};
  static const int Kpad[6]   = {768, 832, 896, 1024, 1408, 2944};
  static const int Nreal[6]  = {6, 24, 96, 384, 1536, 6144};
  static const int Npad[6]   = {128, 128, 128, 384, 1536, 6144};
  static const size_t woff[6] = {0, 98304, 204800, 319488, 712704, 2875392};
  static const int yoff[6]   = {0, 6, 30, 126, 510, 2046};
  static const int curoff[6] = {768, 832, 896, 1024, 1408, 0};

  k_convert_x<<<BATCH * 768 / 4 / 256, 256, 0, stream>>>(x, xraw, cur);
  k_zero_pads<<<(BATCH * 130 + 255) / 256, 256, 0, stream>>>(cur);
  for (int i = 0; i < 6; ++i) {
    int tot = Npad[i] * Kpad[i];
    k_convert_w<<<(tot + 255) / 256, 256, 0, stream>>>(W[i], wp + woff[i], Nreal[i],
                                                       Kreal[i], Kpad[i], tot);
  }
  k_inv<<<(NUM_LABELS + 255) / 256, 256, 0, stream>>>(labels, inv);

  for (int i = 0; i < 6; ++i) {
    const unsigned short* A = (i == 0) ? xraw : cur;
    int lda = (i == 0) ? 768 : CURW;
    dim3 grid(BATCH / 128, Npad[i] / 128);
    k_gemm<<<grid, 256, 0, stream>>>(A, lda, wp + woff[i], Kpad[i], bias[i], ybuf,
                                     (i < 5) ? cur : (unsigned short*)nullptr,
                                     Kpad[i], Nreal[i], yoff[i], curoff[i]);
  }

  k_gather<<<(BATCH * NUM_LABELS + 255) / 256, 256, 0, stream>>>(ybuf, inv, out);
}

// Round 2
// 795.486 us; speedup vs baseline: 1.0352x; 1.0352x over previous
//
#include <hip/hip_runtime.h>
#include <hip/hip_bf16.h>

#define BATCH 8192
#define NUM_LABELS 8190
#define CURW 2944   // padded cur width (K for level 5)
#define YW   8192   // ybuf row stride

typedef __attribute__((ext_vector_type(4))) float f32x4;
typedef __attribute__((ext_vector_type(8))) short bf16x8;

#define VMCNT(n) asm volatile("s_waitcnt vmcnt(" #n ")" ::: "memory")
#define BAR() do { asm volatile("" ::: "memory"); __builtin_amdgcn_s_barrier(); asm volatile("" ::: "memory"); } while (0)

// ---------- helpers ----------
__device__ __forceinline__ unsigned short f2bf(float f) {
  unsigned u = __builtin_bit_cast(unsigned, f);
  unsigned r = u + 0x7fffu + ((u >> 16) & 1u);   // RNE; inputs are finite
  return (unsigned short)(r >> 16);
}
__device__ __forceinline__ float bf2f(unsigned short b) {
  return __builtin_bit_cast(float, (unsigned)b << 16);
}
__device__ __forceinline__ void gload_lds16(const void* g, void* l) {
  __builtin_amdgcn_global_load_lds(
      (const __attribute__((address_space(1))) void*)g,
      (__attribute__((address_space(3))) void*)l,
      16, 0, 0);
}

// ---------- x -> bf16 raw + relu'd cur ----------
__global__ void k_convert_x(const float* __restrict__ x,
                            unsigned short* __restrict__ xraw,
                            unsigned short* __restrict__ cur) {
  int i = blockIdx.x * 256 + threadIdx.x;
  const int total = BATCH * 768 / 4;
  if (i >= total) return;
  float4 v = ((const float4*)x)[i];
  int e = i * 4;
  int row = e / 768;
  int col = e - row * 768;
  ushort4 a, c;
  a.x = f2bf(v.x); a.y = f2bf(v.y); a.z = f2bf(v.z); a.w = f2bf(v.w);
  c.x = f2bf(fmaxf(v.x, 0.f)); c.y = f2bf(fmaxf(v.y, 0.f));
  c.z = f2bf(fmaxf(v.z, 0.f)); c.w = f2bf(fmaxf(v.w, 0.f));
  *(ushort4*)(xraw + e) = a;
  *(ushort4*)(cur + (size_t)row * CURW + col) = c;
}

// ---------- zero the K-pad columns of cur ----------
__global__ void k_zero_pads(unsigned short* __restrict__ cur) {
  const int PP = 130;  // 58 + 40 + 32 pad cols per row
  int i = blockIdx.x * 256 + threadIdx.x;
  if (i >= BATCH * PP) return;
  int row = i / PP, p = i - row * PP;
  int col = p < 58 ? 774 + p : (p < 98 ? 856 + (p - 58) : 992 + (p - 98));
  cur[(size_t)row * CURW + col] = 0;
}

// ---------- padded-col -> real-col map ----------
__device__ __forceinline__ int pad2real(int kp) {
  if (kp < 774)  return kp;               // x(768) + y0(6)
  if (kp < 832)  return -1;               // pad
  if (kp < 856)  return 774 + (kp - 832); // y1(24)
  if (kp < 896)  return -1;
  if (kp < 992)  return 798 + (kp - 896); // y2(96)
  if (kp < 1024) return -1;
  if (kp < 1408) return 894 + (kp - 1024);  // y3(384)
  return 1278 + (kp - 1408);                // y4(1536) -> up to 2814
}

__global__ void k_convert_w(const float* __restrict__ W, unsigned short* __restrict__ Wp,
                            int Nreal, int Kreal, int Kpad, int total) {
  int i = blockIdx.x * 256 + threadIdx.x;
  if (i >= total) return;
  int n = i / Kpad, kp = i - n * Kpad;
  int kr = pad2real(kp);
  float v = 0.f;
  if (n < Nreal && kr >= 0) v = W[(size_t)n * Kreal + kr];
  Wp[i] = f2bf(v);
}

// ---------- inverse permutation ----------
__global__ void k_inv(const int* __restrict__ labels, int* __restrict__ inv) {
  int t = blockIdx.x * 256 + threadIdx.x;
  if (t < NUM_LABELS) inv[labels[t]] = t;
}

// ---------- small-level GEMM (levels 0-3): 128x128 tile, 4 waves ----------
__global__ __launch_bounds__(256, 2) void k_gemm(
    const unsigned short* __restrict__ A, int lda,
    const unsigned short* __restrict__ B, int ldb,
    const float* __restrict__ bias,
    unsigned short* __restrict__ ybuf,
    unsigned short* __restrict__ curout,
    int K, int Nreal, int yoff, int curoff) {
  __shared__ unsigned short Asmem[128 * 64];
  __shared__ unsigned short Bsmem[128 * 64];
  const int tid = threadIdx.x;
  const int lane = tid & 63;
  const int wid = tid >> 6;
  const int wr = wid >> 1, wc = wid & 1;
  const int brow = blockIdx.x * 128;
  const int bcol = blockIdx.y * 128;

  f32x4 acc[4][4] = {};

  for (int k0 = 0; k0 < K; k0 += 64) {
#pragma unroll
    for (int p = 0; p < 4; ++p) {
      int ch = wid * 4 + p;
      int eo = ch * 512 + lane * 8;
      int r = eo >> 6;
      int col = eo & 63;
      gload_lds16(A + (size_t)(brow + r) * lda + k0 + col, Asmem + ch * 512);
      gload_lds16(B + (size_t)(bcol + r) * ldb + k0 + col, Bsmem + ch * 512);
    }
    __syncthreads();
#pragma unroll
    for (int kk = 0; kk < 2; ++kk) {
      bf16x8 af[4], bfr[4];
      int colk = kk * 32 + (lane >> 4) * 8;
#pragma unroll
      for (int m = 0; m < 4; ++m)
        af[m] = *(const bf16x8*)(Asmem + (wr * 64 + m * 16 + (lane & 15)) * 64 + colk);
#pragma unroll
      for (int n = 0; n < 4; ++n)
        bfr[n] = *(const bf16x8*)(Bsmem + (wc * 64 + n * 16 + (lane & 15)) * 64 + colk);
#pragma unroll
      for (int m = 0; m < 4; ++m)
#pragma unroll
        for (int n = 0; n < 4; ++n)
          acc[m][n] = __builtin_amdgcn_mfma_f32_16x16x32_bf16(af[m], bfr[n], acc[m][n], 0, 0, 0);
    }
    __syncthreads();
  }

#pragma unroll
  for (int n = 0; n < 4; ++n) {
    int col = bcol + wc * 64 + n * 16 + (lane & 15);
    if (col >= Nreal) continue;
    float bv = bias[col];
#pragma unroll
    for (int m = 0; m < 4; ++m) {
#pragma unroll
      for (int j = 0; j < 4; ++j) {
        int row = brow + wr * 64 + m * 16 + (lane >> 4) * 4 + j;
        float y = acc[m][n][j] + bv;
        ybuf[(size_t)row * YW + yoff + col] = f2bf(y);
        if (curout) curout[(size_t)row * CURW + curoff + col] = f2bf(fmaxf(y, 0.f));
      }
    }
  }
}

// ---------- big-level GEMM (levels 4-5): 256x256 tile, 8 waves, 8-phase ----------
// T2 swizzle: LDS row-major [128][64] bf16 per operand-half; physical 16B slot p of
// row r holds logical col-slot p^(r&7). Stage pre-swizzles the GLOBAL source col;
// ds_read XORs the col. vmcnt(2) only at phases 4/8 (counted, never 0 mid-loop).
__global__ __launch_bounds__(512, 2) void k_gemm256(
    const unsigned short* __restrict__ A, int lda,
    const unsigned short* __restrict__ B, int ldb,
    const float* __restrict__ bias,
    unsigned short* __restrict__ ybuf,
    unsigned short* __restrict__ curout,
    int K, int MT, int yoff, int curoff) {
  __shared__ __align__(16) unsigned short lds[65536];  // 128 KiB: A[2][2][128][64] | B[2][2][128][64]
  const int tid = threadIdx.x;
  const int l = tid & 63;
  const int w = tid >> 6;          // 0..7
  const int wr = w >> 2;           // 0..1  (M half)
  const int wc = w & 3;            // 0..3  (N quarter)
  const int l15 = l & 15;
  const int q8 = (l >> 4) * 8;
  const int sx = (l & 7) << 3;                    // read-side XOR (elems)
  const int swz = ((l & 7) ^ (l >> 3)) * 8;       // stage-source swizzled col (elems)

  // XCD-aware block swizzle (grid size is a multiple of 8)
  const int nwg = gridDim.x;
  const int cpx = nwg >> 3;
  const int bid = blockIdx.x;
  const int s = (bid & 7) * cpx + (bid >> 3);
  const int im = s % MT, in = s / MT;
  const int brow = im * 256, bcol = in * 256;

  const unsigned short* gA = A + (size_t)(brow + w * 8 + (l >> 3)) * lda + swz;
  const unsigned short* gB = B + (size_t)(bcol + w * 8 + (l >> 3)) * ldb + swz;

  unsigned short* const ldsp = lds;

  auto stageA = [&](int buf, int h, int kt) {
    const unsigned short* g = gA + (size_t)(h * 128) * lda + kt * 64;
    unsigned short* d = ldsp + buf * 16384 + h * 8192 + w * 512;
    gload_lds16(g, d);
    gload_lds16(g + (size_t)64 * lda, d + 4096);
  };
  auto stageB = [&](int buf, int h, int kt) {
    const unsigned short* g = gB + (size_t)(h * 128) * ldb + kt * 64;
    unsigned short* d = ldsp + 32768 + buf * 16384 + h * 8192 + w * 512;
    gload_lds16(g, d);
    gload_lds16(g + (size_t)64 * ldb, d + 4096);
  };

  // per-buf LDS regions this wave reads
  const unsigned short* Arg[2] = { ldsp + wr * 8192, ldsp + 16384 + wr * 8192 };
  const unsigned short* Brg[2] = { ldsp + 32768 + (wc >> 1) * 8192, ldsp + 49152 + (wc >> 1) * 8192 };
  const int brB = (wc & 1) * 64;

  f32x4 acc[8][4] = {};
  bf16x8 aF[2][4], bF[2][4];

  auto ldA = [&](const unsigned short* R, int mhalf) {
#pragma unroll
    for (int kk = 0; kk < 2; ++kk)
#pragma unroll
      for (int m = 0; m < 4; ++m) {
        int r = mhalf * 64 + m * 16 + l15;
        int ck = kk * 32 + q8;
        aF[kk][m] = *(const bf16x8*)(R + r * 64 + (ck ^ sx));
      }
  };
  auto ldB = [&](const unsigned short* R, int nbase) {
#pragma unroll
    for (int kk = 0; kk < 2; ++kk)
#pragma unroll
      for (int n = 0; n < 2; ++n) {
        int r = brB + (nbase + n) * 16 + l15;
        int ck = kk * 32 + q8;
        bF[kk][nbase + n] = *(const bf16x8*)(R + r * 64 + (ck ^ sx));
      }
  };
  auto MMA = [&](int mbase, int nbase) {   // 16 MFMA
    __builtin_amdgcn_s_setprio(1);
#pragma unroll
    for (int kk = 0; kk < 2; ++kk)
#pragma unroll
      for (int m = 0; m < 4; ++m)
#pragma unroll
        for (int n = 0; n < 2; ++n)
          acc[mbase + m][nbase + n] = __builtin_amdgcn_mfma_f32_16x16x32_bf16(
              aF[kk][m], bF[kk][nbase + n], acc[mbase + m][nbase + n], 0, 0, 0);
    __builtin_amdgcn_s_setprio(0);
  };

  const int KT = K >> 6;    // even (22 or 46)
  const int NT2 = KT >> 1;

  // prologue: K-tile 0 -> buf0 (4 halves), K-tile 1 A.h0 -> buf1
  stageA(0, 0, 0); stageA(0, 1, 0); stageB(0, 0, 0); stageB(0, 1, 0);
  stageA(1, 0, 1);
  VMCNT(2);
  BAR();

  for (int it = 0; it < NT2; ++it) {
    const int kt1 = 2 * it + 1, kt2 = 2 * it + 2, kt3 = 2 * it + 3;
    const bool more = (it + 1 < NT2);
    // ---- phases 1-4: compute buf0 (K-tile 2it) ----
    ldA(Arg[0], 0); ldB(Brg[0], 0);           // P1
    stageA(1, 1, kt1);
    BAR(); MMA(0, 0); BAR();
    ldB(Brg[0], 2);                           // P2
    stageB(1, 0, kt1);
    BAR(); MMA(0, 2); BAR();
    ldA(Arg[0], 1);                           // P3
    stageB(1, 1, kt1);
    BAR(); MMA(4, 0); BAR();
    if (more) { stageA(0, 0, kt2); VMCNT(2); }  // P4
    else      { VMCNT(0); }
    BAR(); MMA(4, 2); BAR();
    // ---- phases 5-8: compute buf1 (K-tile 2it+1) ----
    ldA(Arg[1], 0); ldB(Brg[1], 0);           // P5
    if (more) stageA(0, 1, kt2);
    BAR(); MMA(0, 0); BAR();
    ldB(Brg[1], 2);                           // P6
    if (more) stageB(0, 0, kt2);
    BAR(); MMA(0, 2); BAR();
    ldA(Arg[1], 1);                           // P7
    if (more) stageB(0, 1, kt2);
    BAR(); MMA(4, 0); BAR();
    if (more) { stageA(1, 0, kt3); VMCNT(2); }  // P8
    BAR(); MMA(4, 2); BAR();
  }

  // epilogue
  const int j4 = (l >> 4) * 4;
#pragma unroll
  for (int n = 0; n < 4; ++n) {
    int col = bcol + wc * 64 + n * 16 + l15;
    float bv = bias[col];
#pragma unroll
    for (int m = 0; m < 8; ++m) {
      int rowb = brow + wr * 128 + m * 16 + j4;
#pragma unroll
      for (int j = 0; j < 4; ++j) {
        float y = acc[m][n][j] + bv;
        ybuf[(size_t)(rowb + j) * YW + yoff + col] = f2bf(y);
        if (curout) curout[(size_t)(rowb + j) * CURW + curoff + col] = f2bf(fmaxf(y, 0.f));
      }
    }
  }
}

// ---------- final gather: out[row][c] = ybuf[row][inv[c]] ----------
__global__ void k_gather(const unsigned short* __restrict__ ybuf,
                         const int* __restrict__ inv,
                         float* __restrict__ out) {
  int i = blockIdx.x * 256 + threadIdx.x;
  if (i >= BATCH * NUM_LABELS) return;
  int row = i / NUM_LABELS;
  int c = i - row * NUM_LABELS;
  out[i] = bf2f(ybuf[(size_t)row * YW + inv[c]]);
}

// ---------- launch ----------
extern "C" void kernel_launch(void* const* d_in, const int* in_sizes, int n_in,
                              void* d_out, int out_size, void* d_ws, size_t ws_size,
                              hipStream_t stream) {
  const float* x = (const float*)d_in[0];
  const float* W[6];
  const float* bias[6];
  for (int i = 0; i < 6; ++i) {
    W[i] = (const float*)d_in[1 + 2 * i];
    bias[i] = (const float*)d_in[2 + 2 * i];
  }
  const int* labels = (const int*)d_in[13];
  float* out = (float*)d_out;

  char* ws = (char*)d_ws;
  unsigned short* xraw = (unsigned short*)(ws);
  unsigned short* cur  = (unsigned short*)(ws + 12582912);
  unsigned short* wp   = (unsigned short*)(ws + 60817408);
  unsigned short* ybuf = (unsigned short*)(ws + 102744064);
  int* inv             = (int*)(ws + 236961792);

  static const int Kreal[6]  = {768, 774, 798, 894, 1278, 2814};
  static const int Kpad[6]   = {768, 832, 896, 1024, 1408, 2944};
  static const int Nreal[6]  = {6, 24, 96, 384, 1536, 6144};
  static const int Npad[6]   = {128, 128, 128, 384, 1536, 6144};
  static const size_t woff[6] = {0, 98304, 204800, 319488, 712704, 2875392};
  static const int yoff[6]   = {0, 6, 30, 126, 510, 2046};
  static const int curoff[6] = {768, 832, 896, 1024, 1408, 0};

  k_convert_x<<<BATCH * 768 / 4 / 256, 256, 0, stream>>>(x, xraw, cur);
  k_zero_pads<<<(BATCH * 130 + 255) / 256, 256, 0, stream>>>(cur);
  for (int i = 0; i < 6; ++i) {
    int tot = Npad[i] * Kpad[i];
    k_convert_w<<<(tot + 255) / 256, 256, 0, stream>>>(W[i], wp + woff[i], Nreal[i],
                                                       Kreal[i], Kpad[i], tot);
  }
  k_inv<<<(NUM_LABELS + 255) / 256, 256, 0, stream>>>(labels, inv);

  // levels 0-3: 128^2 kernel
  for (int i = 0; i < 4; ++i) {
    dim3 grid(BATCH / 128, Npad[i] / 128);
    k_gemm<<<grid, 256, 0, stream>>>(cur == nullptr ? nullptr : (i == 0 ? xraw : cur),
                                     (i == 0) ? 768 : CURW,
                                     wp + woff[i], Kpad[i], bias[i], ybuf,
                                     cur, Kpad[i], Nreal[i], yoff[i], curoff[i]);
  }
  // levels 4-5: 256^2 8-phase kernel
  for (int i = 4; i < 6; ++i) {
    int nwg = (BATCH / 256) * (Npad[i] / 256);
    k_gemm256<<<nwg, 512, 0, stream>>>(cur, CURW, wp + woff[i], Kpad[i], bias[i], ybuf,
                                       (i < 5) ? cur : (unsigned short*)nullptr,
                                       Kpad[i], BATCH / 256, yoff[i], curoff[i]);
  }

  k_gather<<<(BATCH * NUM_LABELS + 255) / 256, 256, 0, stream>>>(ybuf, inv, out);
}

// Round 3
// 670.716 us; speedup vs baseline: 1.2278x; 1.1860x over previous
//
#include <hip/hip_runtime.h>
#include <hip/hip_bf16.h>

#define BATCH 8192
#define NUM_LABELS 8190
#define CURW 2944   // padded cur width (K for level 5)
#define YW   8192   // ybuf row stride

typedef __attribute__((ext_vector_type(4))) float f32x4;
typedef __attribute__((ext_vector_type(8))) short bf16x8;

#define VMCNT(n) asm volatile("s_waitcnt vmcnt(" #n ")" ::: "memory")
#define BAR() do { asm volatile("" ::: "memory"); __builtin_amdgcn_s_barrier(); asm volatile("" ::: "memory"); } while (0)
#define LGKM0() do { asm volatile("s_waitcnt lgkmcnt(0)" ::: "memory"); __builtin_amdgcn_sched_barrier(0); } while (0)

// ---------- helpers ----------
__device__ __forceinline__ unsigned short f2bf(float f) {
  unsigned u = __builtin_bit_cast(unsigned, f);
  unsigned r = u + 0x7fffu + ((u >> 16) & 1u);   // RNE; inputs are finite
  return (unsigned short)(r >> 16);
}
__device__ __forceinline__ float bf2f(unsigned short b) {
  return __builtin_bit_cast(float, (unsigned)b << 16);
}
__device__ __forceinline__ void gload_lds16(const void* g, void* l) {
  __builtin_amdgcn_global_load_lds(
      (const __attribute__((address_space(1))) void*)g,
      (__attribute__((address_space(3))) void*)l,
      16, 0, 0);
}

// ---------- x -> bf16 raw + relu'd cur ----------
__global__ void k_convert_x(const float* __restrict__ x,
                            unsigned short* __restrict__ xraw,
                            unsigned short* __restrict__ cur) {
  int i = blockIdx.x * 256 + threadIdx.x;
  const int total = BATCH * 768 / 4;
  if (i >= total) return;
  float4 v = ((const float4*)x)[i];
  int e = i * 4;
  int row = e / 768;
  int col = e - row * 768;
  ushort4 a, c;
  a.x = f2bf(v.x); a.y = f2bf(v.y); a.z = f2bf(v.z); a.w = f2bf(v.w);
  c.x = f2bf(fmaxf(v.x, 0.f)); c.y = f2bf(fmaxf(v.y, 0.f));
  c.z = f2bf(fmaxf(v.z, 0.f)); c.w = f2bf(fmaxf(v.w, 0.f));
  *(ushort4*)(xraw + e) = a;
  *(ushort4*)(cur + (size_t)row * CURW + col) = c;
}

// ---------- zero the K-pad columns of cur ----------
__global__ void k_zero_pads(unsigned short* __restrict__ cur) {
  const int PP = 130;
  int i = blockIdx.x * 256 + threadIdx.x;
  if (i >= BATCH * PP) return;
  int row = i / PP, p = i - row * PP;
  int col = p < 58 ? 774 + p : (p < 98 ? 856 + (p - 58) : 992 + (p - 98));
  cur[(size_t)row * CURW + col] = 0;
}

// ---------- padded-col -> real-col map ----------
__device__ __forceinline__ int pad2real(int kp) {
  if (kp < 774)  return kp;
  if (kp < 832)  return -1;
  if (kp < 856)  return 774 + (kp - 832);
  if (kp < 896)  return -1;
  if (kp < 992)  return 798 + (kp - 896);
  if (kp < 1024) return -1;
  if (kp < 1408) return 894 + (kp - 1024);
  return 1278 + (kp - 1408);
}

__global__ void k_convert_w(const float* __restrict__ W, unsigned short* __restrict__ Wp,
                            int Nreal, int Kreal, int Kpad, int total) {
  int i = blockIdx.x * 256 + threadIdx.x;
  if (i >= total) return;
  int n = i / Kpad, kp = i - n * Kpad;
  int kr = pad2real(kp);
  float v = 0.f;
  if (n < Nreal && kr >= 0) v = W[(size_t)n * Kreal + kr];
  Wp[i] = f2bf(v);
}

// ---------- inverse permutation ----------
__global__ void k_inv(const int* __restrict__ labels, int* __restrict__ inv) {
  int t = blockIdx.x * 256 + threadIdx.x;
  if (t < NUM_LABELS) inv[labels[t]] = t;
}

// ---------- small-level GEMM (levels 0-3): 128x128 tile, 4 waves ----------
__global__ __launch_bounds__(256, 2) void k_gemm(
    const unsigned short* __restrict__ A, int lda,
    const unsigned short* __restrict__ B, int ldb,
    const float* __restrict__ bias,
    unsigned short* __restrict__ ybuf,
    unsigned short* __restrict__ curout,
    int K, int Nreal, int yoff, int curoff) {
  __shared__ unsigned short Asmem[128 * 64];
  __shared__ unsigned short Bsmem[128 * 64];
  const int tid = threadIdx.x;
  const int lane = tid & 63;
  const int wid = tid >> 6;
  const int wr = wid >> 1, wc = wid & 1;
  const int brow = blockIdx.x * 128;
  const int bcol = blockIdx.y * 128;

  f32x4 acc[4][4] = {};

  for (int k0 = 0; k0 < K; k0 += 64) {
#pragma unroll
    for (int p = 0; p < 4; ++p) {
      int ch = wid * 4 + p;
      int eo = ch * 512 + lane * 8;
      int r = eo >> 6;
      int col = eo & 63;
      gload_lds16(A + (size_t)(brow + r) * lda + k0 + col, Asmem + ch * 512);
      gload_lds16(B + (size_t)(bcol + r) * ldb + k0 + col, Bsmem + ch * 512);
    }
    __syncthreads();
#pragma unroll
    for (int kk = 0; kk < 2; ++kk) {
      bf16x8 af[4], bfr[4];
      int colk = kk * 32 + (lane >> 4) * 8;
#pragma unroll
      for (int m = 0; m < 4; ++m)
        af[m] = *(const bf16x8*)(Asmem + (wr * 64 + m * 16 + (lane & 15)) * 64 + colk);
#pragma unroll
      for (int n = 0; n < 4; ++n)
        bfr[n] = *(const bf16x8*)(Bsmem + (wc * 64 + n * 16 + (lane & 15)) * 64 + colk);
#pragma unroll
      for (int m = 0; m < 4; ++m)
#pragma unroll
        for (int n = 0; n < 4; ++n)
          acc[m][n] = __builtin_amdgcn_mfma_f32_16x16x32_bf16(af[m], bfr[n], acc[m][n], 0, 0, 0);
    }
    __syncthreads();
  }

#pragma unroll
  for (int n = 0; n < 4; ++n) {
    int col = bcol + wc * 64 + n * 16 + (lane & 15);
    if (col >= Nreal) continue;
    float bv = bias[col];
#pragma unroll
    for (int m = 0; m < 4; ++m) {
#pragma unroll
      for (int j = 0; j < 4; ++j) {
        int row = brow + wr * 64 + m * 16 + (lane >> 4) * 4 + j;
        float y = acc[m][n][j] + bv;
        ybuf[(size_t)row * YW + yoff + col] = f2bf(y);
        if (curout) curout[(size_t)row * CURW + curoff + col] = f2bf(fmaxf(y, 0.f));
      }
    }
  }
}

// ---------- big-level GEMM (levels 4-5): 256x256 tile, 8 waves, 8-phase ----------
// Deep-prefetch schedule: each buffer's halves staged >=3 phases before the
// vmcnt(6) that consumes them. Ledger (2 loads/stage-call, steady state):
//   P7: B0(t3) P8: B1(t3),A0(t3) P1': A1(t3) P3': B0(t4) P4': B1(t4),A0(t4)
//   -> 14 outstanding at P4' vmcnt(6): retires oldest 8 = t3 complete.
// Buffer liveness: B half free after P2/P6, A half free after P3/P7.
__global__ __launch_bounds__(512, 2) void k_gemm256(
    const unsigned short* __restrict__ A, int lda,
    const unsigned short* __restrict__ B, int ldb,
    const float* __restrict__ bias,
    unsigned short* __restrict__ ybuf,
    unsigned short* __restrict__ curout,
    int K, int MT, int yoff, int curoff) {
  __shared__ __align__(16) unsigned short lds[65536];  // 128 KiB
  const int tid = threadIdx.x;
  const int l = tid & 63;
  const int w = tid >> 6;
  const int wr = w >> 2;
  const int wc = w & 3;
  const int l15 = l & 15;
  const int q8 = (l >> 4) * 8;
  const int sx = (l & 7) << 3;
  const int swz = ((l & 7) ^ (l >> 3)) * 8;

  const int nwg = gridDim.x;
  const int cpx = nwg >> 3;
  const int bid = blockIdx.x;
  const int s = (bid & 7) * cpx + (bid >> 3);
  const int im = s % MT, in = s / MT;
  const int brow = im * 256, bcol = in * 256;

  const unsigned short* gA = A + (size_t)(brow + w * 8 + (l >> 3)) * lda + swz;
  const unsigned short* gB = B + (size_t)(bcol + w * 8 + (l >> 3)) * ldb + swz;

  unsigned short* const ldsp = lds;

  auto stageA = [&](int buf, int h, int kt) {
    const unsigned short* g = gA + (size_t)(h * 128) * lda + kt * 64;
    unsigned short* d = ldsp + buf * 16384 + h * 8192 + w * 512;
    gload_lds16(g, d);
    gload_lds16(g + (size_t)64 * lda, d + 4096);
  };
  auto stageB = [&](int buf, int h, int kt) {
    const unsigned short* g = gB + (size_t)(h * 128) * ldb + kt * 64;
    unsigned short* d = ldsp + 32768 + buf * 16384 + h * 8192 + w * 512;
    gload_lds16(g, d);
    gload_lds16(g + (size_t)64 * ldb, d + 4096);
  };

  const unsigned short* Arg[2] = { ldsp + wr * 8192, ldsp + 16384 + wr * 8192 };
  const unsigned short* Brg[2] = { ldsp + 32768 + (wc >> 1) * 8192, ldsp + 49152 + (wc >> 1) * 8192 };
  const int brB = (wc & 1) * 64;

  f32x4 acc[8][4] = {};
  bf16x8 aF[2][4], bF[2][4];

  auto ldA = [&](const unsigned short* R, int mhalf) {
#pragma unroll
    for (int kk = 0; kk < 2; ++kk)
#pragma unroll
      for (int m = 0; m < 4; ++m) {
        int r = mhalf * 64 + m * 16 + l15;
        int ck = kk * 32 + q8;
        aF[kk][m] = *(const bf16x8*)(R + r * 64 + (ck ^ sx));
      }
  };
  auto ldB = [&](const unsigned short* R, int nbase) {
#pragma unroll
    for (int kk = 0; kk < 2; ++kk)
#pragma unroll
      for (int n = 0; n < 2; ++n) {
        int r = brB + (nbase + n) * 16 + l15;
        int ck = kk * 32 + q8;
        bF[kk][nbase + n] = *(const bf16x8*)(R + r * 64 + (ck ^ sx));
      }
  };
  auto MMA = [&](int mbase, int nbase) {
    __builtin_amdgcn_s_setprio(1);
#pragma unroll
    for (int kk = 0; kk < 2; ++kk)
#pragma unroll
      for (int m = 0; m < 4; ++m)
#pragma unroll
        for (int n = 0; n < 2; ++n)
          acc[mbase + m][nbase + n] = __builtin_amdgcn_mfma_f32_16x16x32_bf16(
              aF[kk][m], bF[kk][nbase + n], acc[mbase + m][nbase + n], 0, 0, 0);
    __builtin_amdgcn_s_setprio(0);
  };

  const int KT = K >> 6;
  const int NT2 = KT >> 1;

  // prologue: t0 complete (8 loads) + t1 partial B0,B1,A0 (6 loads)
  stageB(0, 0, 0); stageB(0, 1, 0); stageA(0, 0, 0); stageA(0, 1, 0);
  stageB(1, 0, 1); stageB(1, 1, 1); stageA(1, 0, 1);
  VMCNT(6);          // retire t0's 8, leave t1's 6 in flight
  BAR();
  ldB(Brg[0], 0);    // preload bF[0..1] from buf0

  for (int it = 0; it < NT2; ++it) {
    const bool more = (it + 1 < NT2);
    const int t1 = 2 * it + 1, t2 = 2 * it + 2, t3 = 2 * it + 3;
    // P1: 8 ds_reads + finish t1 staging
    ldA(Arg[0], 0); stageA(1, 1, t1);
    BAR(); LGKM0(); MMA(0, 0); BAR();
    // P2: 4 ds_reads
    ldB(Brg[0], 2);
    BAR(); LGKM0(); MMA(0, 2); BAR();
    // P3: 8 ds_reads + begin t2 staging (buf0.B free after P2)
    ldA(Arg[0], 1);
    if (more) stageB(0, 0, t2);
    BAR(); LGKM0(); MMA(4, 0); BAR();
    // P4: finish most of t2 staging; counted vmcnt -> t1 landed; preload buf1 B
    if (more) { stageB(0, 1, t2); stageA(0, 0, t2); VMCNT(6); }
    else      { VMCNT(0); }
    BAR(); LGKM0(); MMA(4, 2); ldB(Brg[1], 0); BAR();
    // P5: 8 ds_reads + last half of t2 (buf0.A free after P3)
    ldA(Arg[1], 0);
    if (more) stageA(0, 1, t2);
    BAR(); LGKM0(); MMA(0, 0); BAR();
    // P6: 4 ds_reads
    ldB(Brg[1], 2);
    BAR(); LGKM0(); MMA(0, 2); BAR();
    // P7: 8 ds_reads + begin t3 staging (buf1.B free after P6)
    ldA(Arg[1], 1);
    if (more) stageB(1, 0, t3);
    BAR(); LGKM0(); MMA(4, 0); BAR();
    // P8: stage t3; counted vmcnt -> t2 landed; preload next buf0 B
    if (more) { stageB(1, 1, t3); stageA(1, 0, t3); VMCNT(6); }
    BAR(); LGKM0(); MMA(4, 2);
    if (more) ldB(Brg[0], 0);
    BAR();
  }

  // epilogue: n innermost for write combining; bias hoisted
  const int j4 = (l >> 4) * 4;
  float bv[4];
#pragma unroll
  for (int n = 0; n < 4; ++n) bv[n] = bias[bcol + wc * 64 + n * 16 + l15];
#pragma unroll
  for (int m = 0; m < 8; ++m) {
    int rowb = brow + wr * 128 + m * 16 + j4;
#pragma unroll
    for (int j = 0; j < 4; ++j) {
      size_t rbase = (size_t)(rowb + j);
#pragma unroll
      for (int n = 0; n < 4; ++n) {
        int col = bcol + wc * 64 + n * 16 + l15;
        float y = acc[m][n][j] + bv[n];
        ybuf[rbase * YW + yoff + col] = f2bf(y);
        if (curout) curout[rbase * CURW + curoff + col] = f2bf(fmaxf(y, 0.f));
      }
    }
  }
}

// ---------- final gather: out[row][c] = ybuf[row][inv[c]], float2 stores ----------
__global__ void k_gather(const unsigned short* __restrict__ ybuf,
                         const int* __restrict__ inv,
                         float* __restrict__ out) {
  const int half = NUM_LABELS / 2;   // 4095
  int i = blockIdx.x * 256 + threadIdx.x;
  if (i >= BATCH * half) return;
  int row = i / half;
  int c2 = (i - row * half) * 2;
  int2 iv = *(const int2*)(inv + c2);
  const unsigned short* yr = ybuf + (size_t)row * YW;
  float2 v;
  v.x = bf2f(yr[iv.x]);
  v.y = bf2f(yr[iv.y]);
  *(float2*)(out + (size_t)row * NUM_LABELS + c2) = v;
}

// ---------- launch ----------
extern "C" void kernel_launch(void* const* d_in, const int* in_sizes, int n_in,
                              void* d_out, int out_size, void* d_ws, size_t ws_size,
                              hipStream_t stream) {
  const float* x = (const float*)d_in[0];
  const float* W[6];
  const float* bias[6];
  for (int i = 0; i < 6; ++i) {
    W[i] = (const float*)d_in[1 + 2 * i];
    bias[i] = (const float*)d_in[2 + 2 * i];
  }
  const int* labels = (const int*)d_in[13];
  float* out = (float*)d_out;

  char* ws = (char*)d_ws;
  unsigned short* xraw = (unsigned short*)(ws);
  unsigned short* cur  = (unsigned short*)(ws + 12582912);
  unsigned short* wp   = (unsigned short*)(ws + 60817408);
  unsigned short* ybuf = (unsigned short*)(ws + 102744064);
  int* inv             = (int*)(ws + 236961792);

  static const int Kreal[6]  = {768, 774, 798, 894, 1278, 2814};
  static const int Kpad[6]   = {768, 832, 896, 1024, 1408, 2944};
  static const int Nreal[6]  = {6, 24, 96, 384, 1536, 6144};
  static const int Npad[6]   = {128, 128, 128, 384, 1536, 6144};
  static const size_t woff[6] = {0, 98304, 204800, 319488, 712704, 2875392};
  static const int yoff[6]   = {0, 6, 30, 126, 510, 2046};
  static const int curoff[6] = {768, 832, 896, 1024, 1408, 0};

  k_convert_x<<<BATCH * 768 / 4 / 256, 256, 0, stream>>>(x, xraw, cur);
  k_zero_pads<<<(BATCH * 130 + 255) / 256, 256, 0, stream>>>(cur);
  for (int i = 0; i < 6; ++i) {
    int tot = Npad[i] * Kpad[i];
    k_convert_w<<<(tot + 255) / 256, 256, 0, stream>>>(W[i], wp + woff[i], Nreal[i],
                                                       Kreal[i], Kpad[i], tot);
  }
  k_inv<<<(NUM_LABELS + 255) / 256, 256, 0, stream>>>(labels, inv);

  for (int i = 0; i < 4; ++i) {
    dim3 grid(BATCH / 128, Npad[i] / 128);
    k_gemm<<<grid, 256, 0, stream>>>((i == 0 ? xraw : cur),
                                     (i == 0) ? 768 : CURW,
                                     wp + woff[i], Kpad[i], bias[i], ybuf,
                                     cur, Kpad[i], Nreal[i], yoff[i], curoff[i]);
  }
  for (int i = 4; i < 6; ++i) {
    int nwg = (BATCH / 256) * (Npad[i] / 256);
    k_gemm256<<<nwg, 512, 0, stream>>>(cur, CURW, wp + woff[i], Kpad[i], bias[i], ybuf,
                                       (i < 5) ? cur : (unsigned short*)nullptr,
                                       Kpad[i], BATCH / 256, yoff[i], curoff[i]);
  }

  k_gather<<<(BATCH * (NUM_LABELS / 2) + 255) / 256, 256, 0, stream>>>(ybuf, inv, out);
}

// Round 5
// 635.725 us; speedup vs baseline: 1.2954x; 1.0550x over previous
//
#include <hip/hip_runtime.h>
#include <hip/hip_bf16.h>

#define BATCH 8192
#define NUM_LABELS 8190
#define CURW 2944   // padded cur width (K for level 5)
#define YW   8192   // ybuf row stride

typedef __attribute__((ext_vector_type(4))) float f32x4;
typedef __attribute__((ext_vector_type(8))) short bf16x8;

#define VMCNT(n) asm volatile("s_waitcnt vmcnt(" #n ")" ::: "memory")
#define BAR() do { asm volatile("" ::: "memory"); __builtin_amdgcn_s_barrier(); asm volatile("" ::: "memory"); } while (0)
#define LGKM0() do { asm volatile("s_waitcnt lgkmcnt(0)" ::: "memory"); __builtin_amdgcn_sched_barrier(0); } while (0)

// ---------- helpers ----------
__device__ __forceinline__ unsigned short f2bf(float f) {
  unsigned u = __builtin_bit_cast(unsigned, f);
  unsigned r = u + 0x7fffu + ((u >> 16) & 1u);   // RNE; inputs are finite
  return (unsigned short)(r >> 16);
}
__device__ __forceinline__ float bf2f(unsigned short b) {
  return __builtin_bit_cast(float, (unsigned)b << 16);
}
__device__ __forceinline__ void gload_lds16(const void* g, void* l) {
  __builtin_amdgcn_global_load_lds(
      (const __attribute__((address_space(1))) void*)g,
      (__attribute__((address_space(3))) void*)l,
      16, 0, 0);
}

// ---------- x -> bf16 raw + relu'd cur ----------
__global__ void k_convert_x(const float* __restrict__ x,
                            unsigned short* __restrict__ xraw,
                            unsigned short* __restrict__ cur) {
  int i = blockIdx.x * 256 + threadIdx.x;
  const int total = BATCH * 768 / 4;
  if (i >= total) return;
  float4 v = ((const float4*)x)[i];
  int e = i * 4;
  int row = e / 768;
  int col = e - row * 768;
  ushort4 a, c;
  a.x = f2bf(v.x); a.y = f2bf(v.y); a.z = f2bf(v.z); a.w = f2bf(v.w);
  c.x = f2bf(fmaxf(v.x, 0.f)); c.y = f2bf(fmaxf(v.y, 0.f));
  c.z = f2bf(fmaxf(v.z, 0.f)); c.w = f2bf(fmaxf(v.w, 0.f));
  *(ushort4*)(xraw + e) = a;
  *(ushort4*)(cur + (size_t)row * CURW + col) = c;
}

// ---------- zero the K-pad columns of cur ----------
__global__ void k_zero_pads(unsigned short* __restrict__ cur) {
  const int PP = 130;
  int i = blockIdx.x * 256 + threadIdx.x;
  if (i >= BATCH * PP) return;
  int row = i / PP, p = i - row * PP;
  int col = p < 58 ? 774 + p : (p < 98 ? 856 + (p - 58) : 992 + (p - 98));
  cur[(size_t)row * CURW + col] = 0;
}

// ---------- padded-col -> real-col map ----------
__device__ __forceinline__ int pad2real(int kp) {
  if (kp < 774)  return kp;
  if (kp < 832)  return -1;
  if (kp < 856)  return 774 + (kp - 832);
  if (kp < 896)  return -1;
  if (kp < 992)  return 798 + (kp - 896);
  if (kp < 1024) return -1;
  if (kp < 1408) return 894 + (kp - 1024);
  return 1278 + (kp - 1408);
}

__global__ void k_convert_w(const float* __restrict__ W, unsigned short* __restrict__ Wp,
                            int Nreal, int Kreal, int Kpad, int total) {
  int i = blockIdx.x * 256 + threadIdx.x;
  if (i >= total) return;
  int n = i / Kpad, kp = i - n * Kpad;
  int kr = pad2real(kp);
  float v = 0.f;
  if (n < Nreal && kr >= 0) v = W[(size_t)n * Kreal + kr];
  Wp[i] = f2bf(v);
}

// ---------- inverse permutation ----------
__global__ void k_inv(const int* __restrict__ labels, int* __restrict__ inv) {
  int t = blockIdx.x * 256 + threadIdx.x;
  if (t < NUM_LABELS) inv[labels[t]] = t;
}

// ---------- fused levels 0-2: per-32-row block, x staged in LDS once ----------
// LDS rows stride 1000 elems. Level 0 consumes RAW x; afterwards the x-part is
// relu'd IN PLACE (bf16 relu == bf16(relu(x))) before levels 1-2 read it.
__global__ __launch_bounds__(256, 2) void k_fused_small(
    const unsigned short* __restrict__ xraw,
    const unsigned short* __restrict__ w0p,
    const unsigned short* __restrict__ w1p,
    const unsigned short* __restrict__ w2p,
    const float* __restrict__ b0, const float* __restrict__ b1,
    const float* __restrict__ b2,
    unsigned short* __restrict__ ybuf,
    unsigned short* __restrict__ cur) {
  __shared__ __align__(16) unsigned short As[32 * 1000];
  const int tid = threadIdx.x;
  const int l = tid & 63, w = tid >> 6;
  const int l15 = l & 15, q8 = (l >> 4) * 8;
  const int row0 = blockIdx.x * 32;
  const int mi = w >> 1;        // m-tile 0..1
  const int nj0 = w & 1;        // n stripe

  // stage RAW xraw rows + zero cols [768,992)
  {
    const int r = tid >> 3, c8 = tid & 7;
    const unsigned short* src = xraw + (size_t)(row0 + r) * 768 + c8 * 96;
    unsigned short* dst = As + r * 1000 + c8 * 96;
#pragma unroll
    for (int i = 0; i < 12; ++i)
      *(bf16x8*)(dst + i * 8) = *(const bf16x8*)(src + i * 8);
    unsigned short* dz = As + r * 1000 + 768 + c8 * 28;
    ushort4 z = {0, 0, 0, 0};
#pragma unroll
    for (int i = 0; i < 7; ++i) *(ushort4*)(dz + i * 4) = z;
  }
  __syncthreads();

  auto level = [&](int K, int ntiles, int Nr, const unsigned short* W, int ldw,
                   const float* bias, int ycol, int ccol) {
    for (int n = nj0; n < ntiles; n += 2) {
      f32x4 acc = {0.f, 0.f, 0.f, 0.f};
      const unsigned short* wrow = W + (size_t)(n * 16 + l15) * ldw + q8;
      const unsigned short* arow = As + (mi * 16 + l15) * 1000 + q8;
#pragma unroll 2
      for (int k0 = 0; k0 < K; k0 += 32) {
        bf16x8 af = *(const bf16x8*)(arow + k0);
        bf16x8 bf = *(const bf16x8*)(wrow + k0);
        acc = __builtin_amdgcn_mfma_f32_16x16x32_bf16(af, bf, acc, 0, 0, 0);
      }
      int col = n * 16 + l15;
      if (col < Nr) {
        float bv = bias[col];
#pragma unroll
        for (int j = 0; j < 4; ++j) {
          int rl = mi * 16 + (l >> 4) * 4 + j;
          float y = acc[j] + bv;
          ybuf[(size_t)(row0 + rl) * YW + ycol + col] = f2bf(y);
          As[rl * 1000 + ccol + col] = f2bf(fmaxf(y, 0.f));
        }
      }
    }
    __syncthreads();
  };

  level(768, 1, 6,  w0p, 768, b0, 0,  768);

  // relu the x-part of As in place (level 0 used raw x; levels 1-2 need relu(x))
  {
    const int r = tid >> 3, c8 = tid & 7;
    unsigned short* p = As + r * 1000 + c8 * 96;
#pragma unroll
    for (int i = 0; i < 12; ++i) {
      bf16x8 v = *(bf16x8*)(p + i * 8);
#pragma unroll
      for (int j = 0; j < 8; ++j)
        if (((unsigned short)v[j]) & 0x8000u) v[j] = 0;
      *(bf16x8*)(p + i * 8) = v;
    }
  }
  __syncthreads();

  level(832, 2, 24, w1p, 832, b1, 6,  832);
  level(896, 6, 96, w2p, 896, b2, 30, 896);

  // flush LDS cols [768,992) -> cur
  {
    const int r = tid >> 3, c8 = tid & 7;
    const unsigned short* srcl = As + r * 1000 + 768 + c8 * 28;
    unsigned short* dstg = cur + (size_t)(row0 + r) * CURW + 768 + c8 * 28;
#pragma unroll
    for (int i = 0; i < 7; ++i)
      *(ushort4*)(dstg + i * 4) = *(const ushort4*)(srcl + i * 4);
  }
}

// ---------- level-3 GEMM: 128x128 tile, 4 waves ----------
__global__ __launch_bounds__(256, 2) void k_gemm(
    const unsigned short* __restrict__ A, int lda,
    const unsigned short* __restrict__ B, int ldb,
    const float* __restrict__ bias,
    unsigned short* __restrict__ ybuf,
    unsigned short* __restrict__ curout,
    int K, int Nreal, int yoff, int curoff) {
  __shared__ unsigned short Asmem[128 * 64];
  __shared__ unsigned short Bsmem[128 * 64];
  const int tid = threadIdx.x;
  const int lane = tid & 63;
  const int wid = tid >> 6;
  const int wr = wid >> 1, wc = wid & 1;
  const int brow = blockIdx.x * 128;
  const int bcol = blockIdx.y * 128;

  f32x4 acc[4][4] = {};

  for (int k0 = 0; k0 < K; k0 += 64) {
#pragma unroll
    for (int p = 0; p < 4; ++p) {
      int ch = wid * 4 + p;
      int eo = ch * 512 + lane * 8;
      int r = eo >> 6;
      int col = eo & 63;
      gload_lds16(A + (size_t)(brow + r) * lda + k0 + col, Asmem + ch * 512);
      gload_lds16(B + (size_t)(bcol + r) * ldb + k0 + col, Bsmem + ch * 512);
    }
    __syncthreads();
#pragma unroll
    for (int kk = 0; kk < 2; ++kk) {
      bf16x8 af[4], bfr[4];
      int colk = kk * 32 + (lane >> 4) * 8;
#pragma unroll
      for (int m = 0; m < 4; ++m)
        af[m] = *(const bf16x8*)(Asmem + (wr * 64 + m * 16 + (lane & 15)) * 64 + colk);
#pragma unroll
      for (int n = 0; n < 4; ++n)
        bfr[n] = *(const bf16x8*)(Bsmem + (wc * 64 + n * 16 + (lane & 15)) * 64 + colk);
#pragma unroll
      for (int m = 0; m < 4; ++m)
#pragma unroll
        for (int n = 0; n < 4; ++n)
          acc[m][n] = __builtin_amdgcn_mfma_f32_16x16x32_bf16(af[m], bfr[n], acc[m][n], 0, 0, 0);
    }
    __syncthreads();
  }

#pragma unroll
  for (int n = 0; n < 4; ++n) {
    int col = bcol + wc * 64 + n * 16 + (lane & 15);
    if (col >= Nreal) continue;
    float bv = bias[col];
#pragma unroll
    for (int m = 0; m < 4; ++m) {
#pragma unroll
      for (int j = 0; j < 4; ++j) {
        int row = brow + wr * 64 + m * 16 + (lane >> 4) * 4 + j;
        float y = acc[m][n][j] + bv;
        ybuf[(size_t)row * YW + yoff + col] = f2bf(y);
        if (curout) curout[(size_t)row * CURW + curoff + col] = f2bf(fmaxf(y, 0.f));
      }
    }
  }
}

// ---------- big-level GEMM (levels 4-5): 256x256 tile, 8 waves, 8-phase ----------
// 2D XCD ownership: XCD k (= bid&7) owns im in [4k,4k+4); all XCDs share the
// same B panels per round. Deep vmcnt(6) schedule.
__global__ __launch_bounds__(512, 2) void k_gemm256(
    const unsigned short* __restrict__ A, int lda,
    const unsigned short* __restrict__ B, int ldb,
    const float* __restrict__ bias,
    unsigned short* __restrict__ ybuf,
    unsigned short* __restrict__ curout,
    int K, int yoff, int curoff) {
  __shared__ __align__(16) unsigned short lds[65536];  // 128 KiB
  const int tid = threadIdx.x;
  const int l = tid & 63;
  const int w = tid >> 6;
  const int wr = w >> 2;
  const int wc = w & 3;
  const int l15 = l & 15;
  const int q8 = (l >> 4) * 8;
  const int sx = (l & 7) << 3;
  const int swz = ((l & 7) ^ (l >> 3)) * 8;

  const int bid = blockIdx.x;
  const int im = (bid & 7) * 4 + ((bid >> 3) & 3);
  const int in = bid >> 5;
  const int brow = im * 256, bcol = in * 256;

  const unsigned short* gA = A + (size_t)(brow + w * 8 + (l >> 3)) * lda + swz;
  const unsigned short* gB = B + (size_t)(bcol + w * 8 + (l >> 3)) * ldb + swz;

  unsigned short* const ldsp = lds;

  auto stageA = [&](int buf, int h, int kt) {
    const unsigned short* g = gA + (size_t)(h * 128) * lda + kt * 64;
    unsigned short* d = ldsp + buf * 16384 + h * 8192 + w * 512;
    gload_lds16(g, d);
    gload_lds16(g + (size_t)64 * lda, d + 4096);
  };
  auto stageB = [&](int buf, int h, int kt) {
    const unsigned short* g = gB + (size_t)(h * 128) * ldb + kt * 64;
    unsigned short* d = ldsp + 32768 + buf * 16384 + h * 8192 + w * 512;
    gload_lds16(g, d);
    gload_lds16(g + (size_t)64 * ldb, d + 4096);
  };

  const unsigned short* Arg[2] = { ldsp + wr * 8192, ldsp + 16384 + wr * 8192 };
  const unsigned short* Brg[2] = { ldsp + 32768 + (wc >> 1) * 8192, ldsp + 49152 + (wc >> 1) * 8192 };
  const int brB = (wc & 1) * 64;

  f32x4 acc[8][4] = {};
  bf16x8 aF[2][4], bF[2][4];

  auto ldA = [&](const unsigned short* R, int mhalf) {
#pragma unroll
    for (int kk = 0; kk < 2; ++kk)
#pragma unroll
      for (int m = 0; m < 4; ++m) {
        int r = mhalf * 64 + m * 16 + l15;
        int ck = kk * 32 + q8;
        aF[kk][m] = *(const bf16x8*)(R + r * 64 + (ck ^ sx));
      }
  };
  auto ldB = [&](const unsigned short* R, int nbase) {
#pragma unroll
    for (int kk = 0; kk < 2; ++kk)
#pragma unroll
      for (int n = 0; n < 2; ++n) {
        int r = brB + (nbase + n) * 16 + l15;
        int ck = kk * 32 + q8;
        bF[kk][nbase + n] = *(const bf16x8*)(R + r * 64 + (ck ^ sx));
      }
  };
  auto MMA = [&](int mbase, int nbase) {
    __builtin_amdgcn_s_setprio(1);
#pragma unroll
    for (int kk = 0; kk < 2; ++kk)
#pragma unroll
      for (int m = 0; m < 4; ++m)
#pragma unroll
        for (int n = 0; n < 2; ++n)
          acc[mbase + m][nbase + n] = __builtin_amdgcn_mfma_f32_16x16x32_bf16(
              aF[kk][m], bF[kk][nbase + n], acc[mbase + m][nbase + n], 0, 0, 0);
    __builtin_amdgcn_s_setprio(0);
  };

  const int KT = K >> 6;
  const int NT2 = KT >> 1;

  // prologue: t0 complete (8 loads) + t1 partial B0,B1,A0 (6 loads)
  stageB(0, 0, 0); stageB(0, 1, 0); stageA(0, 0, 0); stageA(0, 1, 0);
  stageB(1, 0, 1); stageB(1, 1, 1); stageA(1, 0, 1);
  VMCNT(6);
  BAR();
  ldB(Brg[0], 0);

  for (int it = 0; it < NT2; ++it) {
    const bool more = (it + 1 < NT2);
    const int t1 = 2 * it + 1, t2 = 2 * it + 2, t3 = 2 * it + 3;
    ldA(Arg[0], 0); stageA(1, 1, t1);
    BAR(); LGKM0(); MMA(0, 0); BAR();
    ldB(Brg[0], 2);
    BAR(); LGKM0(); MMA(0, 2); BAR();
    ldA(Arg[0], 1);
    if (more) stageB(0, 0, t2);
    BAR(); LGKM0(); MMA(4, 0); BAR();
    if (more) { stageB(0, 1, t2); stageA(0, 0, t2); VMCNT(6); }
    else      { VMCNT(0); }
    BAR(); LGKM0(); MMA(4, 2); ldB(Brg[1], 0); BAR();
    ldA(Arg[1], 0);
    if (more) stageA(0, 1, t2);
    BAR(); LGKM0(); MMA(0, 0); BAR();
    ldB(Brg[1], 2);
    BAR(); LGKM0(); MMA(0, 2); BAR();
    ldA(Arg[1], 1);
    if (more) stageB(1, 0, t3);
    BAR(); LGKM0(); MMA(4, 0); BAR();
    if (more) { stageB(1, 1, t3); stageA(1, 0, t3); VMCNT(6); }
    BAR(); LGKM0(); MMA(4, 2);
    if (more) ldB(Brg[0], 0);
    BAR();
  }

  // epilogue
  const int j4 = (l >> 4) * 4;
  float bv[4];
#pragma unroll
  for (int n = 0; n < 4; ++n) bv[n] = bias[bcol + wc * 64 + n * 16 + l15];
#pragma unroll
  for (int m = 0; m < 8; ++m) {
    int rowb = brow + wr * 128 + m * 16 + j4;
#pragma unroll
    for (int j = 0; j < 4; ++j) {
      size_t rbase = (size_t)(rowb + j);
#pragma unroll
      for (int n = 0; n < 4; ++n) {
        int col = bcol + wc * 64 + n * 16 + l15;
        float y = acc[m][n][j] + bv[n];
        ybuf[rbase * YW + yoff + col] = f2bf(y);
        if (curout) curout[rbase * CURW + curoff + col] = f2bf(fmaxf(y, 0.f));
      }
    }
  }
}

// ---------- final gather ----------
__global__ void k_gather(const unsigned short* __restrict__ ybuf,
                         const int* __restrict__ inv,
                         float* __restrict__ out) {
  const int half = NUM_LABELS / 2;   // 4095
  int i = blockIdx.x * 256 + threadIdx.x;
  if (i >= BATCH * half) return;
  int row = i / half;
  int c2 = (i - row * half) * 2;
  int2 iv = *(const int2*)(inv + c2);
  const unsigned short* yr = ybuf + (size_t)row * YW;
  float2 v;
  v.x = bf2f(yr[iv.x]);
  v.y = bf2f(yr[iv.y]);
  *(float2*)(out + (size_t)row * NUM_LABELS + c2) = v;
}

// ---------- launch ----------
extern "C" void kernel_launch(void* const* d_in, const int* in_sizes, int n_in,
                              void* d_out, int out_size, void* d_ws, size_t ws_size,
                              hipStream_t stream) {
  const float* x = (const float*)d_in[0];
  const float* W[6];
  const float* bias[6];
  for (int i = 0; i < 6; ++i) {
    W[i] = (const float*)d_in[1 + 2 * i];
    bias[i] = (const float*)d_in[2 + 2 * i];
  }
  const int* labels = (const int*)d_in[13];
  float* out = (float*)d_out;

  char* ws = (char*)d_ws;
  unsigned short* xraw = (unsigned short*)(ws);
  unsigned short* cur  = (unsigned short*)(ws + 12582912);
  unsigned short* wp   = (unsigned short*)(ws + 60817408);
  unsigned short* ybuf = (unsigned short*)(ws + 102744064);
  int* inv             = (int*)(ws + 236961792);

  static const int Kreal[6]  = {768, 774, 798, 894, 1278, 2814};
  static const int Kpad[6]   = {768, 832, 896, 1024, 1408, 2944};
  static const int Nreal[6]  = {6, 24, 96, 384, 1536, 6144};
  static const int Npad[6]   = {128, 128, 128, 384, 1536, 6144};
  static const size_t woff[6] = {0, 98304, 204800, 319488, 712704, 2875392};
  static const int yoff[6]   = {0, 6, 30, 126, 510, 2046};
  static const int curoff[6] = {768, 832, 896, 1024, 1408, 0};

  k_convert_x<<<BATCH * 768 / 4 / 256, 256, 0, stream>>>(x, xraw, cur);
  k_zero_pads<<<(BATCH * 130 + 255) / 256, 256, 0, stream>>>(cur);
  for (int i = 0; i < 6; ++i) {
    int tot = Npad[i] * Kpad[i];
    k_convert_w<<<(tot + 255) / 256, 256, 0, stream>>>(W[i], wp + woff[i], Nreal[i],
                                                       Kreal[i], Kpad[i], tot);
  }
  k_inv<<<(NUM_LABELS + 255) / 256, 256, 0, stream>>>(labels, inv);

  // levels 0-2 fused
  k_fused_small<<<BATCH / 32, 256, 0, stream>>>(
      xraw, wp + woff[0], wp + woff[1], wp + woff[2],
      bias[0], bias[1], bias[2], ybuf, cur);

  // level 3: 128^2 kernel
  {
    dim3 grid(BATCH / 128, Npad[3] / 128);
    k_gemm<<<grid, 256, 0, stream>>>(cur, CURW, wp + woff[3], Kpad[3], bias[3], ybuf,
                                     cur, Kpad[3], Nreal[3], yoff[3], curoff[3]);
  }
  // levels 4-5: 256^2 8-phase kernel, 2D-XCD decode
  for (int i = 4; i < 6; ++i) {
    int nwg = (BATCH / 256) * (Npad[i] / 256);
    k_gemm256<<<nwg, 512, 0, stream>>>(cur, CURW, wp + woff[i], Kpad[i], bias[i], ybuf,
                                       (i < 5) ? cur : (unsigned short*)nullptr,
                                       Kpad[i], yoff[i], curoff[i]);
  }

  k_gather<<<(BATCH * (NUM_LABELS / 2) + 255) / 256, 256, 0, stream>>>(ybuf, inv, out);
}